// Round 6
// baseline (26.081 us; speedup 1.0000x reference)
//
#include <hip/hip_runtime.h>

// MosaicSDF: N=1024 points, G=512 grids, K=7 (343 nodes/grid).
// R6 = R5 + vectorized phase-2 loads:
//   prep  : repack vals (512,343) -> ws (512,400): 49 subrows of 8
//           (7 data + 0-pad), 16B-aligned -> phase 2 uses dwordx4.
//   fused : block (128 thr = 2 waves) per point. Phase 1 sweeps 512 grids,
//           ballot-scan compacts active (rx,ry,rz,gwr) into LDS float4.
//           Phase 2: one lane per active pair, separable distance tables,
//           2x float4 loads per (i,j) subrow, dz2[7]=4 kills the pad node.
//   No atomics, no memset, deterministic.

#define NPTS   1024
#define NGRIDS 512
#define GSTRIDE 400            // floats per grid row in repacked ws
#define STEP   (1.0f / 6.0f)
#define FSQRT(x) __builtin_amdgcn_sqrtf(x)

__global__ __launch_bounds__(256) void msdf_prep(
    const float* __restrict__ vals,      // (512,343)
    float* __restrict__ wv)              // (512,400)
{
    const int idx = blockIdx.x * 256 + threadIdx.x;   // [0, 512*400)
    if (idx >= NGRIDS * GSTRIDE) return;
    const int g = idx / GSTRIDE;
    const int r = idx - g * GSTRIDE;
    float v = 0.0f;
    if (r < 392) {
        const int s = r >> 3;            // subrow 0..48
        const int l = r & 7;             // 0..7
        if (l < 7) v = vals[g * 343 + s * 7 + l];
    }
    wv[idx] = v;
}

__global__ __launch_bounds__(128) void msdf_fused(
    const float* __restrict__ points,    // (N,3)
    const float* __restrict__ centers,   // (G,3)
    const float* __restrict__ scales,    // (G,)
    const float* __restrict__ wv,        // (512,400) repacked vals
    float* __restrict__ out)             // (N,)
{
    __shared__ float4 s_pair[2][256];    // (rx,ry,rz,gwr) per active, per half
    __shared__ unsigned short s_gid[2][256];
    __shared__ int   s_c[2];
    __shared__ float s_d[2];
    __shared__ float s_a[2];

    const int n    = blockIdx.x;
    const int t    = threadIdx.x;
    const int h    = t >> 6;             // wave half: grids [h*256, h*256+256)
    const int lane = t & 63;

    const float px = points[n * 3 + 0];
    const float py = points[n * 3 + 1];
    const float pz = points[n * 3 + 2];

    // ---- Phase 1: activity sweep + ballot-scan compaction ----
    float dsum  = 0.0f;
    int   cbase = 0;
    #pragma unroll
    for (int r = 0; r < 4; ++r) {
        const int g = h * 256 + r * 64 + lane;
        const float invs = 1.0f / scales[g];
        const float rx = (px - centers[g * 3 + 0]) * invs;
        const float ry = (py - centers[g * 3 + 1]) * invs;
        const float rz = (pz - centers[g * 3 + 2]) * invs;
        const float gwr = 1.0f - FSQRT(rx * rx + ry * ry + rz * rz);
        const bool  act = (gwr > 0.0f);
        const unsigned long long m = __ballot(act);
        if (act) {
            const int pos = cbase + (int)__popcll(m & ((1ull << lane) - 1ull));
            s_pair[h][pos] = make_float4(rx, ry, rz, gwr);
            s_gid[h][pos]  = (unsigned short)g;
            dsum += gwr;
        }
        cbase += (int)__popcll(m);
    }
    #pragma unroll
    for (int off = 32; off >= 1; off >>= 1) dsum += __shfl_xor(dsum, off);
    if (lane == 0) { s_c[h] = cbase; s_d[h] = dsum; }
    __syncthreads();

    // ---- Phase 2: one lane per active pair ----
    const int   c0  = s_c[0];
    const int   C   = c0 + s_c[1];
    const float den = s_d[0] + s_d[1];

    float acc = 0.0f;
    for (int a = h * 64 + lane; a < C; a += 128) {
        const int    ia = (a < c0) ? 0 : 1;
        const int    ja = (a < c0) ? a : a - c0;
        const float4 pr = s_pair[ia][ja];
        const int    g  = (int)s_gid[ia][ja];
        const float  rx = pr.x, ry = pr.y, rz = pr.z, gwr = pr.w;

        // Separable per-axis squared distances (static indices -> regs).
        float dy2[7], dz2[8];
        #pragma unroll
        for (int j = 0; j < 7; ++j) { const float d = ry - j * STEP; dy2[j] = d * d; }
        #pragma unroll
        for (int l = 0; l < 7; ++l) { const float d = rz - l * STEP; dz2[l] = d * d; }
        dz2[7] = 4.0f;                   // pad node: d2 > 1 -> weight 0

        const float* __restrict__ gv = wv + g * GSTRIDE;
        float wsum = 0.0f, vsum = 0.0f;
        float tx = rx;
        #pragma unroll 1
        for (int i = 0; i < 7; ++i) {
            const float dx2 = tx * tx;
            tx -= STEP;
            const float* __restrict__ gvi = gv + i * 56;   // 7 subrows of 8
            #pragma unroll
            for (int j = 0; j < 7; ++j) {
                const float dxy = dx2 + dy2[j];
                const float4 v0 = *(const float4*)(gvi + j * 8);
                const float4 v1 = *(const float4*)(gvi + j * 8 + 4);
                #pragma unroll
                for (int l = 0; l < 8; ++l) {
                    const float d2 = dxy + dz2[l];
                    const float wt = (d2 <= 1.0f) ? FSQRT(d2) : 0.0f;
                    const float vv = (l < 4) ? ((const float*)&v0)[l & 3]
                                             : ((const float*)&v1)[l & 3];
                    wsum += wt;
                    vsum  = fmaf(wt, vv, vsum);
                }
            }
        }
        const float interp = (wsum > 0.0f) ? (vsum / wsum) : 0.0f;
        acc += interp * gwr;
    }

    #pragma unroll
    for (int off = 32; off >= 1; off >>= 1) acc += __shfl_xor(acc, off);
    if (lane == 0) s_a[h] = acc;
    __syncthreads();
    if (t == 0)
        out[n] = (den > 0.0f) ? ((s_a[0] + s_a[1]) / den) : 0.0f;
}

extern "C" void kernel_launch(void* const* d_in, const int* in_sizes, int n_in,
                              void* d_out, int out_size, void* d_ws, size_t ws_size,
                              hipStream_t stream) {
    const float* points  = (const float*)d_in[0];   // (1024,3)
    const float* centers = (const float*)d_in[1];   // (512,3)
    const float* scales  = (const float*)d_in[2];   // (512,)
    const float* vals    = (const float*)d_in[3];   // (512,7,7,7)
    float* out = (float*)d_out;                     // (1024,)
    float* wv  = (float*)d_ws;                      // (512,400) repacked

    msdf_prep<<<(NGRIDS * GSTRIDE + 255) / 256, 256, 0, stream>>>(vals, wv);
    msdf_fused<<<NPTS, 128, 0, stream>>>(points, centers, scales, wv, out);
}

// Round 7
// 17.033 us; speedup vs baseline: 1.5312x; 1.5312x over previous
//
#include <hip/hip_runtime.h>

// MosaicSDF: N=1024 points, G=512 grids, K=7 (343 nodes/grid).
// R7: single kernel, block (128 thr = 2 waves) per point.
//   Phase 1 (as R5, but tables in LDS): sweep 512 grids, ballot-scan
//     compact active (rx,ry,rz,gwr)+gid into LDS; wave-reduce den.
//   Phase 2: 8-lane group per active pair. Group stages its pair's
//     343-float row global->LDS (8 consecutive floats per 8 lanes,
//     coalesced runs), software-pipelined (issue chunk c+1's loads
//     before computing chunk c). Compute: lane sub = x-slab i, static
//     dy2[]/dz2[] register tables, 49 nodes/lane, 3-step group reduce.
//   No barriers in the phase-2 loop (each group stages the rows it
//   computes), no atomics, no workspace, one dispatch.

#define NPTS   1024
#define NGRIDS 512
#define STEP   (1.0f / 6.0f)
#define FSQRT(x) __builtin_amdgcn_sqrtf(x)

__global__ __launch_bounds__(128) void msdf_fused(
    const float* __restrict__ points,    // (N,3)
    const float* __restrict__ centers,   // (G,3)
    const float* __restrict__ scales,    // (G,)
    const float* __restrict__ vals,      // (G,343)
    float* __restrict__ out)             // (N,)
{
    __shared__ float  s_v[16 * 343];     // 16 staged rows (2 waves x 8 groups)
    __shared__ float4 s_pair[2][256];    // (rx,ry,rz,gwr) per active, per half
    __shared__ unsigned short s_gid[2][256];
    __shared__ int   s_c[2];
    __shared__ float s_d[2];
    __shared__ float s_a[2];

    const int n    = blockIdx.x;
    const int t    = threadIdx.x;
    const int h    = t >> 6;             // wave half: grids [h*256, h*256+256)
    const int lane = t & 63;
    const int grp  = lane >> 3;          // 8-lane group id (pair slot)
    const int sub  = lane & 7;           // slab / stage sub-lane

    // Stage centers+scales into LDS (aliased with s_v; phase-1 only).
    float* s_cen = s_v;                  // 1536 floats
    float* s_scl = s_v + 1536;           // 512 floats
    {
        const float4* c4 = (const float4*)centers;       // 384 float4
        #pragma unroll
        for (int i = 0; i < 3; ++i) ((float4*)s_cen)[t + i * 128] = c4[t + i * 128];
        ((float4*)s_scl)[t] = ((const float4*)scales)[t]; // 128 float4... t<128 ok
    }
    const float px = points[n * 3 + 0];  // uniform -> scalar loads
    const float py = points[n * 3 + 1];
    const float pz = points[n * 3 + 2];
    __syncthreads();

    // ---- Phase 1: activity sweep + ballot-scan compaction ----
    float dsum  = 0.0f;
    int   cbase = 0;
    #pragma unroll
    for (int r = 0; r < 4; ++r) {
        const int g = h * 256 + r * 64 + lane;
        const float invs = 1.0f / s_scl[g];
        const float rx = (px - s_cen[g * 3 + 0]) * invs;
        const float ry = (py - s_cen[g * 3 + 1]) * invs;
        const float rz = (pz - s_cen[g * 3 + 2]) * invs;
        const float gwr = 1.0f - FSQRT(rx * rx + ry * ry + rz * rz);
        const bool  act = (gwr > 0.0f);
        const unsigned long long m = __ballot(act);
        if (act) {
            const int pos = cbase + (int)__popcll(m & ((1ull << lane) - 1ull));
            s_pair[h][pos] = make_float4(rx, ry, rz, gwr);
            s_gid[h][pos]  = (unsigned short)g;
            dsum += gwr;
        }
        cbase += (int)__popcll(m);
    }
    #pragma unroll
    for (int off = 32; off >= 1; off >>= 1) dsum += __shfl_xor(dsum, off);
    if (lane == 0) { s_c[h] = cbase; s_d[h] = dsum; }
    __syncthreads();                     // also: s_cen/s_scl reads done (alias)

    // ---- Phase 2: 8-lane group per pair, LDS-staged rows, pipelined ----
    const int   c0  = s_c[0];
    const int   C   = c0 + s_c[1];
    const float den = s_d[0] + s_d[1];

    const int base = h * 8 + grp;        // this group's pair-slot stride base
    const int nch  = (C > h * 8) ? ((C - h * 8 + 15) >> 4) : 0;
    float* __restrict__ myv = s_v + (h * 8 + grp) * 343;   // group's LDS row

    float rbuf[43];
    float acc = 0.0f;

    auto issueLoads = [&](int c) {
        const int p  = 16 * c + base;
        const int pc = (p < C) ? p : (C - 1);
        const int ia = (pc < c0) ? 0 : 1;
        const int jp = (pc < c0) ? pc : pc - c0;
        const int gid = (int)s_gid[ia][jp];
        const float* __restrict__ grow = vals + gid * 343;
        #pragma unroll
        for (int k = 0; k < 42; ++k) rbuf[k] = grow[sub + 8 * k];
        rbuf[42] = (sub < 7) ? grow[sub + 336] : 0.0f;
    };

    if (nch > 0) {
        issueLoads(0);
        for (int c = 0; c < nch; ++c) {
            // commit staged row to LDS (this group's private row)
            #pragma unroll
            for (int k = 0; k < 42; ++k) myv[sub + 8 * k] = rbuf[k];
            if (sub < 7) myv[sub + 336] = rbuf[42];
            // prefetch next chunk's row while computing this one
            if (c + 1 < nch) issueLoads(c + 1);

            const int p  = 16 * c + base;
            const int pc = (p < C) ? p : (C - 1);
            const int ia = (pc < c0) ? 0 : 1;
            const int jp = (pc < c0) ? pc : pc - c0;
            const float4 pr = s_pair[ia][jp];           // broadcast read
            const float  gw = (p < C) ? pr.w : 0.0f;

            float dy2[7], dz2[7];
            #pragma unroll
            for (int j = 0; j < 7; ++j) { const float d = pr.y - j * STEP; dy2[j] = d * d; }
            #pragma unroll
            for (int l = 0; l < 7; ++l) { const float d = pr.z - l * STEP; dz2[l] = d * d; }

            const int   slab = (sub < 7) ? sub : 6;
            const float dxv  = pr.x - slab * STEP;
            const float dx2  = (sub < 7) ? dxv * dxv : 4.0f;   // sub==7 -> wt 0
            const float* __restrict__ vrow = myv + slab * 49;

            float ws = 0.0f, vs = 0.0f;
            #pragma unroll
            for (int j = 0; j < 7; ++j) {
                const float dxy = dx2 + dy2[j];
                #pragma unroll
                for (int l = 0; l < 7; ++l) {
                    const float d2 = dxy + dz2[l];
                    const float wt = (d2 <= 1.0f) ? FSQRT(d2) : 0.0f;
                    ws += wt;
                    vs  = fmaf(wt, vrow[j * 7 + l], vs);
                }
            }
            #pragma unroll
            for (int off = 4; off >= 1; off >>= 1) {
                ws += __shfl_xor(ws, off);
                vs += __shfl_xor(vs, off);
            }
            const float interp = (ws > 0.0f) ? (vs / ws) : 0.0f;
            if (sub == 0) acc += interp * gw;
        }
    }

    // Sum the 8 group contributions (sub==0 lanes hold partials).
    #pragma unroll
    for (int off = 32; off >= 1; off >>= 1) acc += __shfl_xor(acc, off);
    if (lane == 0) s_a[h] = acc;
    __syncthreads();
    if (t == 0)
        out[n] = (den > 0.0f) ? ((s_a[0] + s_a[1]) / den) : 0.0f;
}

extern "C" void kernel_launch(void* const* d_in, const int* in_sizes, int n_in,
                              void* d_out, int out_size, void* d_ws, size_t ws_size,
                              hipStream_t stream) {
    const float* points  = (const float*)d_in[0];   // (1024,3)
    const float* centers = (const float*)d_in[1];   // (512,3)
    const float* scales  = (const float*)d_in[2];   // (512,)
    const float* vals    = (const float*)d_in[3];   // (512,7,7,7)
    float* out = (float*)d_out;                     // (1024,)

    msdf_fused<<<NPTS, 128, 0, stream>>>(points, centers, scales, vals, out);
}